// Round 2
// baseline (741.004 us; speedup 1.0000x reference)
//
#include <hip/hip_runtime.h>
#include <hip/hip_bf16.h>
#include <stdint.h>

typedef __attribute__((ext_vector_type(8))) short bf16x8;
typedef __attribute__((ext_vector_type(4))) float f32x4;
typedef __attribute__((ext_vector_type(4))) unsigned int u32x4;

__device__ __forceinline__ unsigned short f2bf(float f) {
  union { float f; unsigned int u; } c; c.f = f;
  unsigned int u = c.u;
  u += 0x7FFFu + ((u >> 16) & 1u);   // round-to-nearest-even
  return (unsigned short)(u >> 16);
}
__device__ __forceinline__ float bf2f(unsigned short b) {
  union { unsigned int u; float f; } c; c.u = ((unsigned int)b) << 16;
  return c.f;
}

// ---- convert two fp32 arrays to bf16 (blockIdx.y selects which) ----
__global__ void cvt_x(const float* __restrict__ a, const float* __restrict__ b,
                      unsigned short* __restrict__ oa, unsigned short* __restrict__ ob, int n) {
  const float* src = blockIdx.y ? b : a;
  unsigned short* dst = blockIdx.y ? ob : oa;
  int i = (blockIdx.x * 256 + threadIdx.x) * 8;
  if (i >= n) return;
  float4 v0 = *(const float4*)(src + i);
  float4 v1 = *(const float4*)(src + i + 4);
  u32x4 o;
  o[0] = (unsigned int)f2bf(v0.x) | ((unsigned int)f2bf(v0.y) << 16);
  o[1] = (unsigned int)f2bf(v0.z) | ((unsigned int)f2bf(v0.w) << 16);
  o[2] = (unsigned int)f2bf(v1.x) | ((unsigned int)f2bf(v1.y) << 16);
  o[3] = (unsigned int)f2bf(v1.z) | ((unsigned int)f2bf(v1.w) << 16);
  *(u32x4*)(dst + i) = o;
}

struct WPtrs { const float* p[8]; };

// ---- convert the 8 [128x128] weight matrices to bf16 ----
__global__ void cvt_w(WPtrs w, unsigned short* __restrict__ out) {
  int wi = blockIdx.y;
  int i = (blockIdx.x * 256 + threadIdx.x) * 8;   // 16384 elems -> 8 blocks in x
  const float* src = w.p[wi];
  float4 v0 = *(const float4*)(src + i);
  float4 v1 = *(const float4*)(src + i + 4);
  u32x4 o;
  o[0] = (unsigned int)f2bf(v0.x) | ((unsigned int)f2bf(v0.y) << 16);
  o[1] = (unsigned int)f2bf(v0.z) | ((unsigned int)f2bf(v0.w) << 16);
  o[2] = (unsigned int)f2bf(v1.x) | ((unsigned int)f2bf(v1.y) << 16);
  o[3] = (unsigned int)f2bf(v1.z) | ((unsigned int)f2bf(v1.w) << 16);
  *(u32x4*)(out + wi * 16384 + i) = o;
}

// ---- counting-sort pipeline: histogram, scan (3 kernels), reorder ----
__global__ void hist_k(const int* __restrict__ ei, int* __restrict__ cnt, int E) {
  int e = blockIdx.x * 256 + threadIdx.x;
  if (e < E) atomicAdd(&cnt[ei[E + e]], 1);     // ei row 1 = dst
}

__global__ void scan_a(const int* __restrict__ in, int* __restrict__ incl,
                       int* __restrict__ bsum, int n) {
  __shared__ int sm[1024];
  int i = blockIdx.x * 1024 + threadIdx.x;
  int v = (i < n) ? in[i] : 0;
  sm[threadIdx.x] = v;
  __syncthreads();
  for (int off = 1; off < 1024; off <<= 1) {
    int t = (threadIdx.x >= off) ? sm[threadIdx.x - off] : 0;
    __syncthreads();
    sm[threadIdx.x] += t;
    __syncthreads();
  }
  if (i < n) incl[i] = sm[threadIdx.x];
  if (threadIdx.x == 1023) bsum[blockIdx.x] = sm[1023];
}

__global__ void scan_b(int* __restrict__ bsum, int nb) {
  __shared__ int sm[128];
  int t = threadIdx.x;
  int v = (t < nb) ? bsum[t] : 0;
  sm[t] = v;
  __syncthreads();
  for (int off = 1; off < 128; off <<= 1) {
    int u = (t >= off) ? sm[t - off] : 0;
    __syncthreads();
    sm[t] += u;
    __syncthreads();
  }
  if (t < nb) bsum[t] = sm[t] - v;   // exclusive block offsets
}

__global__ void scan_c(const int* __restrict__ cnt, const int* __restrict__ incl,
                       const int* __restrict__ bexcl, int* __restrict__ rowptr,
                       int* __restrict__ cursor, int n) {
  int i = blockIdx.x * 256 + threadIdx.x;
  if (i >= n) return;
  int e = incl[i] - cnt[i] + bexcl[i >> 10];     // exclusive prefix
  rowptr[i] = e;
  cursor[i] = e;
}

__global__ void reorder_k(const int* __restrict__ ei, int* __restrict__ cursor,
                          int* __restrict__ ssrc, int E) {
  int e = blockIdx.x * 256 + threadIdx.x;
  if (e >= E) return;
  int s = ei[e];          // src
  int d = ei[E + e];      // dst
  int pos = atomicAdd(&cursor[d], 1);
  ssrc[pos] = s;
}

// ---- CSR gather-mean: 16 lanes per node, bf16x8 per lane ----
__global__ void agg_k(const unsigned short* __restrict__ xsrc, const int* __restrict__ rowptr,
                      const int* __restrict__ cnt, const int* __restrict__ ssrc,
                      unsigned short* __restrict__ meanout, int n) {
  int node = blockIdx.x * 16 + (threadIdx.x >> 4);
  if (node >= n) return;
  int q = (threadIdx.x & 15) * 8;     // bf16 element offset within row
  int beg = rowptr[node];
  int deg = cnt[node];
  float a[8] = {0.f,0.f,0.f,0.f,0.f,0.f,0.f,0.f};
  for (int t = 0; t < deg; ++t) {
    int s = ssrc[beg + t];
    u32x4 v = *(const u32x4*)(xsrc + (size_t)s * 128 + q);
    a[0] += bf2f((unsigned short)(v[0] & 0xFFFF)); a[1] += bf2f((unsigned short)(v[0] >> 16));
    a[2] += bf2f((unsigned short)(v[1] & 0xFFFF)); a[3] += bf2f((unsigned short)(v[1] >> 16));
    a[4] += bf2f((unsigned short)(v[2] & 0xFFFF)); a[5] += bf2f((unsigned short)(v[2] >> 16));
    a[6] += bf2f((unsigned short)(v[3] & 0xFFFF)); a[7] += bf2f((unsigned short)(v[3] >> 16));
  }
  float inv = deg > 0 ? 1.0f / (float)deg : 0.0f;
  u32x4 o;
  o[0] = (unsigned int)f2bf(a[0]*inv) | ((unsigned int)f2bf(a[1]*inv) << 16);
  o[1] = (unsigned int)f2bf(a[2]*inv) | ((unsigned int)f2bf(a[3]*inv) << 16);
  o[2] = (unsigned int)f2bf(a[4]*inv) | ((unsigned int)f2bf(a[5]*inv) << 16);
  o[3] = (unsigned int)f2bf(a[6]*inv) | ((unsigned int)f2bf(a[7]*inv) << 16);
  *(u32x4*)(meanout + (size_t)node * 128 + q) = o;
}

// ---- fused dual matmul: out = mean @ Wl^T + x @ Wr^T + bias (+relu, bf16 out) ----
// block = 256 threads (4 waves), tile = 64 rows x 128 cols, wave owns 16 rows.
template<int RELU_BF16>
__global__ __launch_bounds__(256) void lin_k(
    const unsigned short* __restrict__ meanb, const unsigned short* __restrict__ xb,
    const unsigned short* __restrict__ Wl, const unsigned short* __restrict__ Wr,
    const float* __restrict__ bias, void* __restrict__ outp, int n)
{
  // A tiles in LDS, padded row stride 136 bf16 (272B) -> <=2-way bank conflict (free)
  __shared__ unsigned short lds[2 * 64 * 136];
  int n0 = blockIdx.x * 64;
  int tid = threadIdx.x;

  for (int m = 0; m < 2; ++m) {
    const unsigned short* src = m ? xb : meanb;
    unsigned short* dstl = lds + m * 64 * 136;
    #pragma unroll
    for (int it = 0; it < 4; ++it) {
      int li = (it * 256 + tid) * 8;           // 0..8191 bf16 elems
      int r = li >> 7, c = li & 127;
      u32x4 v = {0u, 0u, 0u, 0u};
      int row = n0 + r;
      if (row < n) v = *(const u32x4*)(src + (size_t)row * 128 + c);
      *(u32x4*)(dstl + r * 136 + c) = v;
    }
  }
  __syncthreads();

  int wave = tid >> 6, lane = tid & 63;
  int lr = lane & 15;             // A row-in-16 / B col-in-16
  int kb = (lane >> 4) * 8;       // k sub-offset within the 32-wide K step
  f32x4 acc[8] = {};              // 8 column tiles of 16

  const unsigned short* Alds[2] = { lds, lds + 64 * 136 };
  const unsigned short* Wg[2]   = { Wl, Wr };
  #pragma unroll
  for (int h = 0; h < 2; ++h) {
    const unsigned short* A = Alds[h] + (wave * 16 + lr) * 136 + kb;
    const unsigned short* W = Wg[h] + lr * 128 + kb;
    #pragma unroll
    for (int ks = 0; ks < 4; ++ks) {
      bf16x8 a = *(const bf16x8*)(A + ks * 32);
      #pragma unroll
      for (int jt = 0; jt < 8; ++jt) {
        bf16x8 b = *(const bf16x8*)(W + jt * 16 * 128 + ks * 32);
        acc[jt] = __builtin_amdgcn_mfma_f32_16x16x32_bf16(a, b, acc[jt], 0, 0, 0);
      }
    }
  }

  // C/D layout: col = lane&15, row = (lane>>4)*4 + reg  [verified m89/m91]
  int rbase = n0 + wave * 16 + (lane >> 4) * 4;
  #pragma unroll
  for (int jt = 0; jt < 8; ++jt) {
    int col = jt * 16 + lr;
    float bv = bias[col];
    #pragma unroll
    for (int i = 0; i < 4; ++i) {
      int row = rbase + i;
      if (row < n) {
        float v = acc[jt][i] + bv;
        if (RELU_BF16) {
          v = v > 0.f ? v : 0.f;
          ((unsigned short*)outp)[(size_t)row * 128 + col] = f2bf(v);
        } else {
          ((float*)outp)[(size_t)row * 128 + col] = v;
        }
      }
    }
  }
}

extern "C" void kernel_launch(void* const* d_in, const int* in_sizes, int n_in,
                              void* d_out, int out_size, void* d_ws, size_t ws_size,
                              hipStream_t stream) {
  const float* xp = (const float*)d_in[0];
  const float* xt = (const float*)d_in[1];
  const int* ei_pt = (const int*)d_in[2];
  const int* ei_tp = (const int*)d_in[3];
  WPtrs wp;
  for (int i = 0; i < 8; ++i) wp.p[i] = (const float*)d_in[4 + i];
  const float* bl0_pt = (const float*)d_in[12];
  const float* bl0_tp = (const float*)d_in[13];
  const float* bl1_pt = (const float*)d_in[14];
  const float* bl1_tp = (const float*)d_in[15];
  float* out = (float*)d_out;     // [o_player (N*128) | o_team (N*128)]

  const int N = in_sizes[0] / 128;
  const int E = in_sizes[2] / 2;
  const size_t NB = (size_t)N * 128 * 2;    // bf16 feature matrix bytes

  char* ws = (char*)d_ws;
  size_t off = 0;
  auto alloc = [&](size_t bytes) -> void* {
    off = (off + 255) & ~(size_t)255;
    void* p = ws + off; off += bytes; return p;
  };
  unsigned short* xp_bf  = (unsigned short*)alloc(NB);
  unsigned short* xt_bf  = (unsigned short*)alloc(NB);
  unsigned short* hp_bf  = (unsigned short*)alloc(NB);
  unsigned short* ht_bf  = (unsigned short*)alloc(NB);
  unsigned short* mean_bf= (unsigned short*)alloc(NB);
  unsigned short* wbf    = (unsigned short*)alloc(8 * 16384 * 2);
  int* cnt[2];  int* rowptr[2];  int* cursor[2];  int* ssrc[2];  int* incl[2];  int* bsum[2];
  for (int r = 0; r < 2; ++r) {
    cnt[r]    = (int*)alloc((size_t)N * 4);
    rowptr[r] = (int*)alloc((size_t)N * 4);
    cursor[r] = (int*)alloc((size_t)N * 4);
    incl[r]   = (int*)alloc((size_t)N * 4);
    ssrc[r]   = (int*)alloc((size_t)E * 4);
    bsum[r]   = (int*)alloc(1024);
  }

  const int nx = N * 128;
  // fp32 -> bf16 conversions
  cvt_x<<<dim3((nx / 8 + 255) / 256, 2), 256, 0, stream>>>(xp, xt, xp_bf, xt_bf, nx);
  cvt_w<<<dim3(8, 8), 256, 0, stream>>>(wp, wbf);

  // CSR build per relation (reused by both layers)
  const int SCB = (N + 1023) / 1024;
  for (int r = 0; r < 2; ++r) {
    const int* ei = r ? ei_tp : ei_pt;
    hipMemsetAsync(cnt[r], 0, (size_t)N * 4, stream);
    hist_k<<<(E + 255) / 256, 256, 0, stream>>>(ei, cnt[r], E);
    scan_a<<<SCB, 1024, 0, stream>>>(cnt[r], incl[r], bsum[r], N);
    scan_b<<<1, 128, 0, stream>>>(bsum[r], SCB);
    scan_c<<<(N + 255) / 256, 256, 0, stream>>>(cnt[r], incl[r], bsum[r], rowptr[r], cursor[r], N);
    reorder_k<<<(E + 255) / 256, 256, 0, stream>>>(ei, cursor[r], ssrc[r], E);
  }

  const int AGB = (N + 15) / 16;
  const int LNB = (N + 63) / 64;
  // ---- layer 0 ----
  // h_team = relu(mean_pt(x_player) @ Wl0_pt^T + bl0_pt + x_team @ Wr0_pt^T)
  agg_k<<<AGB, 256, 0, stream>>>(xp_bf, rowptr[0], cnt[0], ssrc[0], mean_bf, N);
  lin_k<1><<<LNB, 256, 0, stream>>>(mean_bf, xt_bf, wbf + 0 * 16384, wbf + 1 * 16384, bl0_pt, ht_bf, N);
  // h_player = relu(mean_tp(x_team) @ Wl0_tp^T + bl0_tp + x_player @ Wr0_tp^T)
  agg_k<<<AGB, 256, 0, stream>>>(xt_bf, rowptr[1], cnt[1], ssrc[1], mean_bf, N);
  lin_k<1><<<LNB, 256, 0, stream>>>(mean_bf, xp_bf, wbf + 2 * 16384, wbf + 3 * 16384, bl0_tp, hp_bf, N);
  // ---- layer 1 ----
  // o_team = mean_pt(h_player) @ Wl1_pt^T + bl1_pt + h_team @ Wr1_pt^T   -> out + N*128
  agg_k<<<AGB, 256, 0, stream>>>(hp_bf, rowptr[0], cnt[0], ssrc[0], mean_bf, N);
  lin_k<0><<<LNB, 256, 0, stream>>>(mean_bf, ht_bf, wbf + 4 * 16384, wbf + 5 * 16384, bl1_pt, out + (size_t)N * 128, N);
  // o_player = mean_tp(h_team) @ Wl1_tp^T + bl1_tp + h_player @ Wr1_tp^T -> out
  agg_k<<<AGB, 256, 0, stream>>>(ht_bf, rowptr[1], cnt[1], ssrc[1], mean_bf, N);
  lin_k<0><<<LNB, 256, 0, stream>>>(mean_bf, hp_bf, wbf + 6 * 16384, wbf + 7 * 16384, bl1_tp, out, N);
}

// Round 3
// 596.135 us; speedup vs baseline: 1.2430x; 1.2430x over previous
//
#include <hip/hip_runtime.h>
#include <hip/hip_bf16.h>
#include <stdint.h>

typedef __attribute__((ext_vector_type(8))) short bf16x8;
typedef __attribute__((ext_vector_type(4))) float f32x4;
typedef __attribute__((ext_vector_type(4))) unsigned int u32x4;

__device__ __forceinline__ unsigned short f2bf(float f) {
  union { float f; unsigned int u; } c; c.f = f;
  unsigned int u = c.u;
  u += 0x7FFFu + ((u >> 16) & 1u);   // round-to-nearest-even
  return (unsigned short)(u >> 16);
}
__device__ __forceinline__ float bf2f(unsigned short b) {
  union { unsigned int u; float f; } c; c.u = ((unsigned int)b) << 16;
  return c.f;
}

// ---- convert two fp32 arrays to bf16 (blockIdx.y selects which) ----
__global__ void cvt_x(const float* __restrict__ a, const float* __restrict__ b,
                      unsigned short* __restrict__ oa, unsigned short* __restrict__ ob, int n) {
  const float* src = blockIdx.y ? b : a;
  unsigned short* dst = blockIdx.y ? ob : oa;
  int i = (blockIdx.x * 256 + threadIdx.x) * 8;
  if (i >= n) return;
  float4 v0 = *(const float4*)(src + i);
  float4 v1 = *(const float4*)(src + i + 4);
  u32x4 o;
  o[0] = (unsigned int)f2bf(v0.x) | ((unsigned int)f2bf(v0.y) << 16);
  o[1] = (unsigned int)f2bf(v0.z) | ((unsigned int)f2bf(v0.w) << 16);
  o[2] = (unsigned int)f2bf(v1.x) | ((unsigned int)f2bf(v1.y) << 16);
  o[3] = (unsigned int)f2bf(v1.z) | ((unsigned int)f2bf(v1.w) << 16);
  *(u32x4*)(dst + i) = o;
}

struct WPtrs { const float* p[8]; };

// ---- convert the 8 [128x128] weight matrices to bf16 ----
__global__ void cvt_w(WPtrs w, unsigned short* __restrict__ out) {
  int wi = blockIdx.y;
  int i = (blockIdx.x * 256 + threadIdx.x) * 8;   // 16384 elems -> 8 blocks in x
  const float* src = w.p[wi];
  float4 v0 = *(const float4*)(src + i);
  float4 v1 = *(const float4*)(src + i + 4);
  u32x4 o;
  o[0] = (unsigned int)f2bf(v0.x) | ((unsigned int)f2bf(v0.y) << 16);
  o[1] = (unsigned int)f2bf(v0.z) | ((unsigned int)f2bf(v0.w) << 16);
  o[2] = (unsigned int)f2bf(v1.x) | ((unsigned int)f2bf(v1.y) << 16);
  o[3] = (unsigned int)f2bf(v1.z) | ((unsigned int)f2bf(v1.w) << 16);
  *(u32x4*)(out + wi * 16384 + i) = o;
}

// ---- counting-sort pipeline: histogram, scan (3 kernels), reorder ----
__global__ void hist_k(const int* __restrict__ ei, int* __restrict__ cnt, int E) {
  int e = blockIdx.x * 256 + threadIdx.x;
  if (e < E) atomicAdd(&cnt[ei[E + e]], 1);     // ei row 1 = dst
}

__global__ void scan_a(const int* __restrict__ in, int* __restrict__ incl,
                       int* __restrict__ bsum, int n) {
  __shared__ int sm[1024];
  int i = blockIdx.x * 1024 + threadIdx.x;
  int v = (i < n) ? in[i] : 0;
  sm[threadIdx.x] = v;
  __syncthreads();
  for (int off = 1; off < 1024; off <<= 1) {
    int t = (threadIdx.x >= off) ? sm[threadIdx.x - off] : 0;
    __syncthreads();
    sm[threadIdx.x] += t;
    __syncthreads();
  }
  if (i < n) incl[i] = sm[threadIdx.x];
  if (threadIdx.x == 1023) bsum[blockIdx.x] = sm[1023];
}

__global__ void scan_b(int* __restrict__ bsum, int nb) {
  __shared__ int sm[128];
  int t = threadIdx.x;
  int v = (t < nb) ? bsum[t] : 0;
  sm[t] = v;
  __syncthreads();
  for (int off = 1; off < 128; off <<= 1) {
    int u = (t >= off) ? sm[t - off] : 0;
    __syncthreads();
    sm[t] += u;
    __syncthreads();
  }
  if (t < nb) bsum[t] = sm[t] - v;   // exclusive block offsets
}

__global__ void scan_c(const int* __restrict__ cnt, const int* __restrict__ incl,
                       const int* __restrict__ bexcl, int* __restrict__ rowptr,
                       int* __restrict__ cursor, int n) {
  int i = blockIdx.x * 256 + threadIdx.x;
  if (i >= n) return;
  int e = incl[i] - cnt[i] + bexcl[i >> 10];     // exclusive prefix
  rowptr[i] = e;
  cursor[i] = e;
}

__global__ void reorder_k(const int* __restrict__ ei, int* __restrict__ cursor,
                          int* __restrict__ ssrc, int E) {
  int e = blockIdx.x * 256 + threadIdx.x;
  if (e >= E) return;
  int s = ei[e];          // src
  int d = ei[E + e];      // dst
  int pos = atomicAdd(&cursor[d], 1);
  ssrc[pos] = s;
}

// ---- CSR gather-mean: 16 lanes per node, bf16x8 per lane ----
__global__ void agg_k(const unsigned short* __restrict__ xsrc, const int* __restrict__ rowptr,
                      const int* __restrict__ cnt, const int* __restrict__ ssrc,
                      unsigned short* __restrict__ meanout, int n) {
  int node = blockIdx.x * 16 + (threadIdx.x >> 4);
  if (node >= n) return;
  int q = (threadIdx.x & 15) * 8;     // bf16 element offset within row
  int beg = rowptr[node];
  int deg = cnt[node];
  float a[8] = {0.f,0.f,0.f,0.f,0.f,0.f,0.f,0.f};
  for (int t = 0; t < deg; ++t) {
    int s = ssrc[beg + t];
    u32x4 v = *(const u32x4*)(xsrc + (size_t)s * 128 + q);
    a[0] += bf2f((unsigned short)(v[0] & 0xFFFF)); a[1] += bf2f((unsigned short)(v[0] >> 16));
    a[2] += bf2f((unsigned short)(v[1] & 0xFFFF)); a[3] += bf2f((unsigned short)(v[1] >> 16));
    a[4] += bf2f((unsigned short)(v[2] & 0xFFFF)); a[5] += bf2f((unsigned short)(v[2] >> 16));
    a[6] += bf2f((unsigned short)(v[3] & 0xFFFF)); a[7] += bf2f((unsigned short)(v[3] >> 16));
  }
  float inv = deg > 0 ? 1.0f / (float)deg : 0.0f;
  u32x4 o;
  o[0] = (unsigned int)f2bf(a[0]*inv) | ((unsigned int)f2bf(a[1]*inv) << 16);
  o[1] = (unsigned int)f2bf(a[2]*inv) | ((unsigned int)f2bf(a[3]*inv) << 16);
  o[2] = (unsigned int)f2bf(a[4]*inv) | ((unsigned int)f2bf(a[5]*inv) << 16);
  o[3] = (unsigned int)f2bf(a[6]*inv) | ((unsigned int)f2bf(a[7]*inv) << 16);
  *(u32x4*)(meanout + (size_t)node * 128 + q) = o;
}

// ---- fused dual matmul: out = mean @ Wl^T + x @ Wr^T + bias (+relu, bf16 out) ----
// block = 256 threads (4 waves), tile = 64 rows x 128 cols.
// Wave w owns all 64 rows x cols [w*32, w*32+32): its 16 B-fragments (64 VGPR)
// are PRELOADED into registers (independent burst) so the MFMA loop has zero
// global loads — fixes the latency-serialization seen in round 2 (MfmaUtil 3%).
template<int RELU_BF16>
__global__ __launch_bounds__(256, 4) void lin_k(
    const unsigned short* __restrict__ meanb, const unsigned short* __restrict__ xb,
    const unsigned short* __restrict__ Wl, const unsigned short* __restrict__ Wr,
    const float* __restrict__ bias, void* __restrict__ outp, int n)
{
  // A tiles in LDS, padded row stride 136 bf16 (272B) -> 2-way bank conflict (free)
  __shared__ unsigned short lds[2 * 64 * 136];
  int n0 = blockIdx.x * 64;
  int tid = threadIdx.x;
  int wave = tid >> 6, lane = tid & 63;
  int lr = lane & 15;             // A row-in-16 / B col-in-16
  int kb = (lane >> 4) * 8;       // k sub-offset within the 32-wide K step

  // ---- preload this wave's 16 B fragments (2 h x 2 jt x 4 ks) ----
  const unsigned short* Wg[2] = { Wl, Wr };
  bf16x8 breg[2][2][4];
  #pragma unroll
  for (int h = 0; h < 2; ++h) {
    const unsigned short* wb = Wg[h] + (size_t)(wave * 32 + lr) * 128 + kb;
    #pragma unroll
    for (int jt = 0; jt < 2; ++jt)
      #pragma unroll
      for (int ks = 0; ks < 4; ++ks)
        breg[h][jt][ks] = *(const bf16x8*)(wb + jt * 16 * 128 + ks * 32);
  }

  // ---- stage A tiles (mean, x) into LDS ----
  #pragma unroll
  for (int m = 0; m < 2; ++m) {
    const unsigned short* src = m ? xb : meanb;
    unsigned short* dstl = lds + m * 64 * 136;
    #pragma unroll
    for (int it = 0; it < 4; ++it) {
      int li = (it * 256 + tid) * 8;           // 0..8191 bf16 elems
      int r = li >> 7, c = li & 127;
      u32x4 v = {0u, 0u, 0u, 0u};
      int row = n0 + r;
      if (row < n) v = *(const u32x4*)(src + (size_t)row * 128 + c);
      *(u32x4*)(dstl + r * 136 + c) = v;
    }
  }
  __syncthreads();

  // ---- pure LDS + register MFMA loop: 32 ds_read_b128, 64 MFMA ----
  f32x4 acc[4][2] = {};           // [row tile][col tile], statically indexed
  #pragma unroll
  for (int h = 0; h < 2; ++h) {
    const unsigned short* Abase = lds + h * 64 * 136 + lr * 136 + kb;
    #pragma unroll
    for (int rt = 0; rt < 4; ++rt) {
      #pragma unroll
      for (int ks = 0; ks < 4; ++ks) {
        bf16x8 a = *(const bf16x8*)(Abase + rt * 16 * 136 + ks * 32);
        acc[rt][0] = __builtin_amdgcn_mfma_f32_16x16x32_bf16(a, breg[h][0][ks], acc[rt][0], 0, 0, 0);
        acc[rt][1] = __builtin_amdgcn_mfma_f32_16x16x32_bf16(a, breg[h][1][ks], acc[rt][1], 0, 0, 0);
      }
    }
  }

  // C/D layout: col = lane&15, row = (lane>>4)*4 + reg  [verified m89/m91]
  #pragma unroll
  for (int jt = 0; jt < 2; ++jt) {
    int col = wave * 32 + jt * 16 + lr;
    float bv = bias[col];
    #pragma unroll
    for (int rt = 0; rt < 4; ++rt) {
      int rbase = n0 + rt * 16 + (lane >> 4) * 4;
      #pragma unroll
      for (int i = 0; i < 4; ++i) {
        int row = rbase + i;
        if (row < n) {
          float v = acc[rt][jt][i] + bv;
          if (RELU_BF16) {
            v = v > 0.f ? v : 0.f;
            ((unsigned short*)outp)[(size_t)row * 128 + col] = f2bf(v);
          } else {
            ((float*)outp)[(size_t)row * 128 + col] = v;
          }
        }
      }
    }
  }
}

extern "C" void kernel_launch(void* const* d_in, const int* in_sizes, int n_in,
                              void* d_out, int out_size, void* d_ws, size_t ws_size,
                              hipStream_t stream) {
  const float* xp = (const float*)d_in[0];
  const float* xt = (const float*)d_in[1];
  const int* ei_pt = (const int*)d_in[2];
  const int* ei_tp = (const int*)d_in[3];
  WPtrs wp;
  for (int i = 0; i < 8; ++i) wp.p[i] = (const float*)d_in[4 + i];
  const float* bl0_pt = (const float*)d_in[12];
  const float* bl0_tp = (const float*)d_in[13];
  const float* bl1_pt = (const float*)d_in[14];
  const float* bl1_tp = (const float*)d_in[15];
  float* out = (float*)d_out;     // [o_player (N*128) | o_team (N*128)]

  const int N = in_sizes[0] / 128;
  const int E = in_sizes[2] / 2;
  const size_t NB = (size_t)N * 128 * 2;    // bf16 feature matrix bytes

  char* ws = (char*)d_ws;
  size_t off = 0;
  auto alloc = [&](size_t bytes) -> void* {
    off = (off + 255) & ~(size_t)255;
    void* p = ws + off; off += bytes; return p;
  };
  unsigned short* xp_bf  = (unsigned short*)alloc(NB);
  unsigned short* xt_bf  = (unsigned short*)alloc(NB);
  unsigned short* hp_bf  = (unsigned short*)alloc(NB);
  unsigned short* ht_bf  = (unsigned short*)alloc(NB);
  unsigned short* mean_bf= (unsigned short*)alloc(NB);
  unsigned short* wbf    = (unsigned short*)alloc(8 * 16384 * 2);
  int* cnt[2];  int* rowptr[2];  int* cursor[2];  int* ssrc[2];  int* incl[2];  int* bsum[2];
  for (int r = 0; r < 2; ++r) {
    cnt[r]    = (int*)alloc((size_t)N * 4);
    rowptr[r] = (int*)alloc((size_t)N * 4);
    cursor[r] = (int*)alloc((size_t)N * 4);
    incl[r]   = (int*)alloc((size_t)N * 4);
    ssrc[r]   = (int*)alloc((size_t)E * 4);
    bsum[r]   = (int*)alloc(1024);
  }

  const int nx = N * 128;
  // fp32 -> bf16 conversions
  cvt_x<<<dim3((nx / 8 + 255) / 256, 2), 256, 0, stream>>>(xp, xt, xp_bf, xt_bf, nx);
  cvt_w<<<dim3(8, 8), 256, 0, stream>>>(wp, wbf);

  // CSR build per relation (reused by both layers)
  const int SCB = (N + 1023) / 1024;
  for (int r = 0; r < 2; ++r) {
    const int* ei = r ? ei_tp : ei_pt;
    hipMemsetAsync(cnt[r], 0, (size_t)N * 4, stream);
    hist_k<<<(E + 255) / 256, 256, 0, stream>>>(ei, cnt[r], E);
    scan_a<<<SCB, 1024, 0, stream>>>(cnt[r], incl[r], bsum[r], N);
    scan_b<<<1, 128, 0, stream>>>(bsum[r], SCB);
    scan_c<<<(N + 255) / 256, 256, 0, stream>>>(cnt[r], incl[r], bsum[r], rowptr[r], cursor[r], N);
    reorder_k<<<(E + 255) / 256, 256, 0, stream>>>(ei, cursor[r], ssrc[r], E);
  }

  const int AGB = (N + 15) / 16;
  const int LNB = (N + 63) / 64;
  // ---- layer 0 ----
  // h_team = relu(mean_pt(x_player) @ Wl0_pt^T + bl0_pt + x_team @ Wr0_pt^T)
  agg_k<<<AGB, 256, 0, stream>>>(xp_bf, rowptr[0], cnt[0], ssrc[0], mean_bf, N);
  lin_k<1><<<LNB, 256, 0, stream>>>(mean_bf, xt_bf, wbf + 0 * 16384, wbf + 1 * 16384, bl0_pt, ht_bf, N);
  // h_player = relu(mean_tp(x_team) @ Wl0_tp^T + bl0_tp + x_player @ Wr0_tp^T)
  agg_k<<<AGB, 256, 0, stream>>>(xt_bf, rowptr[1], cnt[1], ssrc[1], mean_bf, N);
  lin_k<1><<<LNB, 256, 0, stream>>>(mean_bf, xp_bf, wbf + 2 * 16384, wbf + 3 * 16384, bl0_tp, hp_bf, N);
  // ---- layer 1 ----
  // o_team = mean_pt(h_player) @ Wl1_pt^T + bl1_pt + h_team @ Wr1_pt^T   -> out + N*128
  agg_k<<<AGB, 256, 0, stream>>>(hp_bf, rowptr[0], cnt[0], ssrc[0], mean_bf, N);
  lin_k<0><<<LNB, 256, 0, stream>>>(mean_bf, ht_bf, wbf + 4 * 16384, wbf + 5 * 16384, bl1_pt, out + (size_t)N * 128, N);
  // o_player = mean_tp(h_team) @ Wl1_tp^T + bl1_tp + h_player @ Wr1_tp^T -> out
  agg_k<<<AGB, 256, 0, stream>>>(ht_bf, rowptr[1], cnt[1], ssrc[1], mean_bf, N);
  lin_k<0><<<LNB, 256, 0, stream>>>(mean_bf, hp_bf, wbf + 6 * 16384, wbf + 7 * 16384, bl1_tp, out, N);
}

// Round 4
// 563.673 us; speedup vs baseline: 1.3146x; 1.0576x over previous
//
#include <hip/hip_runtime.h>
#include <hip/hip_bf16.h>
#include <stdint.h>

typedef __attribute__((ext_vector_type(8))) short bf16x8;
typedef __attribute__((ext_vector_type(4))) float f32x4;
typedef __attribute__((ext_vector_type(4))) unsigned int u32x4;

__device__ __forceinline__ unsigned short f2bf(float f) {
  union { float f; unsigned int u; } c; c.f = f;
  unsigned int u = c.u;
  u += 0x7FFFu + ((u >> 16) & 1u);   // round-to-nearest-even
  return (unsigned short)(u >> 16);
}
__device__ __forceinline__ float bf2f(unsigned short b) {
  union { unsigned int u; float f; } c; c.u = ((unsigned int)b) << 16;
  return c.f;
}
__device__ __forceinline__ void acc8(const u32x4& v, float* a) {
  a[0] += bf2f((unsigned short)(v[0] & 0xFFFF)); a[1] += bf2f((unsigned short)(v[0] >> 16));
  a[2] += bf2f((unsigned short)(v[1] & 0xFFFF)); a[3] += bf2f((unsigned short)(v[1] >> 16));
  a[4] += bf2f((unsigned short)(v[2] & 0xFFFF)); a[5] += bf2f((unsigned short)(v[2] >> 16));
  a[6] += bf2f((unsigned short)(v[3] & 0xFFFF)); a[7] += bf2f((unsigned short)(v[3] >> 16));
}

// ---- convert two fp32 arrays to bf16 (blockIdx.y selects which) ----
__global__ void cvt_x(const float* __restrict__ a, const float* __restrict__ b,
                      unsigned short* __restrict__ oa, unsigned short* __restrict__ ob, int n) {
  const float* src = blockIdx.y ? b : a;
  unsigned short* dst = blockIdx.y ? ob : oa;
  int i = (blockIdx.x * 256 + threadIdx.x) * 8;
  if (i >= n) return;
  float4 v0 = *(const float4*)(src + i);
  float4 v1 = *(const float4*)(src + i + 4);
  u32x4 o;
  o[0] = (unsigned int)f2bf(v0.x) | ((unsigned int)f2bf(v0.y) << 16);
  o[1] = (unsigned int)f2bf(v0.z) | ((unsigned int)f2bf(v0.w) << 16);
  o[2] = (unsigned int)f2bf(v1.x) | ((unsigned int)f2bf(v1.y) << 16);
  o[3] = (unsigned int)f2bf(v1.z) | ((unsigned int)f2bf(v1.w) << 16);
  *(u32x4*)(dst + i) = o;
}

struct WPtrs { const float* p[8]; };

// ---- convert the 8 [128x128] weight matrices to bf16 ----
__global__ void cvt_w(WPtrs w, unsigned short* __restrict__ out) {
  int wi = blockIdx.y;
  int i = (blockIdx.x * 256 + threadIdx.x) * 8;   // 16384 elems -> 8 blocks in x
  const float* src = w.p[wi];
  float4 v0 = *(const float4*)(src + i);
  float4 v1 = *(const float4*)(src + i + 4);
  u32x4 o;
  o[0] = (unsigned int)f2bf(v0.x) | ((unsigned int)f2bf(v0.y) << 16);
  o[1] = (unsigned int)f2bf(v0.z) | ((unsigned int)f2bf(v0.w) << 16);
  o[2] = (unsigned int)f2bf(v1.x) | ((unsigned int)f2bf(v1.y) << 16);
  o[3] = (unsigned int)f2bf(v1.z) | ((unsigned int)f2bf(v1.w) << 16);
  *(u32x4*)(out + wi * 16384 + i) = o;
}

// ---- counting-sort pipeline, both relations per launch (blockIdx.y) ----
__global__ void hist2_k(const int* __restrict__ ei0, const int* __restrict__ ei1,
                        int* __restrict__ cnt, int E, int N) {
  const int* ei = blockIdx.y ? ei1 : ei0;
  int* c = cnt + blockIdx.y * N;
  int e = blockIdx.x * 256 + threadIdx.x;
  if (e < E) atomicAdd(&c[ei[E + e]], 1);     // ei row 1 = dst
}

__global__ void scan_a2(const int* __restrict__ cnt, int* __restrict__ incl,
                        int* __restrict__ bsum, int n) {
  const int* in = cnt + blockIdx.y * n;
  int* out = incl + blockIdx.y * n;
  int* bs = bsum + blockIdx.y * 128;
  __shared__ int sm[1024];
  int i = blockIdx.x * 1024 + threadIdx.x;
  int v = (i < n) ? in[i] : 0;
  sm[threadIdx.x] = v;
  __syncthreads();
  for (int off = 1; off < 1024; off <<= 1) {
    int t = (threadIdx.x >= off) ? sm[threadIdx.x - off] : 0;
    __syncthreads();
    sm[threadIdx.x] += t;
    __syncthreads();
  }
  if (i < n) out[i] = sm[threadIdx.x];
  if (threadIdx.x == 1023) bs[blockIdx.x] = sm[1023];
}

__global__ void scan_b2(int* __restrict__ bsum, int nb) {
  int* bs = bsum + blockIdx.y * 128;
  __shared__ int sm[128];
  int t = threadIdx.x;
  int v = (t < nb) ? bs[t] : 0;
  sm[t] = v;
  __syncthreads();
  for (int off = 1; off < 128; off <<= 1) {
    int u = (t >= off) ? sm[t - off] : 0;
    __syncthreads();
    sm[t] += u;
    __syncthreads();
  }
  if (t < nb) bs[t] = sm[t] - v;   // exclusive block offsets
}

__global__ void scan_c2(const int* __restrict__ cnt, const int* __restrict__ incl,
                        const int* __restrict__ bsum, int* __restrict__ rowptr,
                        int* __restrict__ cursor, int n) {
  int y = blockIdx.y;
  int i = blockIdx.x * 256 + threadIdx.x;
  if (i >= n) return;
  int e = incl[y * n + i] - cnt[y * n + i] + bsum[y * 128 + (i >> 10)];
  rowptr[y * n + i] = e;
  cursor[y * n + i] = e;
}

__global__ void reorder2_k(const int* __restrict__ ei0, const int* __restrict__ ei1,
                           int* __restrict__ cursor, int* __restrict__ ssrc, int E, int N) {
  const int* ei = blockIdx.y ? ei1 : ei0;
  int* cur = cursor + blockIdx.y * N;
  int* ss = ssrc + blockIdx.y * E;
  int e = blockIdx.x * 256 + threadIdx.x;
  if (e >= E) return;
  int s = ei[e];          // src
  int d = ei[E + e];      // dst
  int pos = atomicAdd(&cur[d], 1);
  ss[pos] = s;
}

// ---- fused gather-mean + dual matmul ----
// out = mean_csr(xsrc) @ Wl^T + xdst @ Wr^T + bias (+relu->bf16 | ->f32)
// block = 256 threads (4 waves), tile = 64 rows x 128 cols; grid.y picks relation.
// Gather-mean is staged straight into the LDS A-tile (no mean_bf round-trip);
// gather loop unrolled x4 for 4 loads in flight (round-2 lesson: 1-deep chains
// leave every pipe idle). Wave w's 16 B fragments preloaded to registers.
struct FusedArgs {
  const unsigned short* xsrc; const unsigned short* xdst;
  const int* rowptr; const int* cnt; const int* ssrc;
  const unsigned short* Wl; const unsigned short* Wr;
  const float* bias; void* out;
};

template<int RELU_BF16>
__global__ __launch_bounds__(256, 4) void fused_k(FusedArgs f0, FusedArgs f1, int n) {
  FusedArgs A = blockIdx.y ? f1 : f0;
  __shared__ unsigned short lds[2 * 64 * 136];   // [mean tile | xdst tile], stride 136
  int n0 = blockIdx.x * 64;
  int tid = threadIdx.x;
  int wave = tid >> 6, lane = tid & 63;
  int lr = lane & 15;             // A row-in-16 / B col-in-16
  int kb = (lane >> 4) * 8;       // k sub-offset within the 32-wide K step

  // ---- phase 1: gather-mean into lds[0] ----
  {
    int g = tid >> 4;             // 16-lane group id = node-in-sweep
    int q = (tid & 15) * 8;       // bf16 column offset
    #pragma unroll
    for (int sweep = 0; sweep < 4; ++sweep) {
      int node = n0 + sweep * 16 + g;
      float a[8] = {0.f,0.f,0.f,0.f,0.f,0.f,0.f,0.f};
      float inv = 0.f;
      if (node < n) {
        int beg = A.rowptr[node];
        int deg = A.cnt[node];
        inv = deg > 0 ? 1.0f / (float)deg : 0.0f;
        int t = 0;
        for (; t + 4 <= deg; t += 4) {
          int s0 = A.ssrc[beg + t], s1 = A.ssrc[beg + t + 1];
          int s2 = A.ssrc[beg + t + 2], s3 = A.ssrc[beg + t + 3];
          u32x4 v0 = *(const u32x4*)(A.xsrc + (size_t)s0 * 128 + q);
          u32x4 v1 = *(const u32x4*)(A.xsrc + (size_t)s1 * 128 + q);
          u32x4 v2 = *(const u32x4*)(A.xsrc + (size_t)s2 * 128 + q);
          u32x4 v3 = *(const u32x4*)(A.xsrc + (size_t)s3 * 128 + q);
          acc8(v0, a); acc8(v1, a); acc8(v2, a); acc8(v3, a);
        }
        for (; t < deg; ++t) {
          int s = A.ssrc[beg + t];
          u32x4 v = *(const u32x4*)(A.xsrc + (size_t)s * 128 + q);
          acc8(v, a);
        }
      }
      u32x4 o;
      o[0] = (unsigned int)f2bf(a[0]*inv) | ((unsigned int)f2bf(a[1]*inv) << 16);
      o[1] = (unsigned int)f2bf(a[2]*inv) | ((unsigned int)f2bf(a[3]*inv) << 16);
      o[2] = (unsigned int)f2bf(a[4]*inv) | ((unsigned int)f2bf(a[5]*inv) << 16);
      o[3] = (unsigned int)f2bf(a[6]*inv) | ((unsigned int)f2bf(a[7]*inv) << 16);
      *(u32x4*)(lds + (sweep * 16 + g) * 136 + q) = o;
    }
  }

  // ---- phase 1b: copy xdst tile into lds[1] ----
  {
    unsigned short* dstl = lds + 64 * 136;
    #pragma unroll
    for (int it = 0; it < 4; ++it) {
      int li = (it * 256 + tid) * 8;
      int r = li >> 7, c = li & 127;
      u32x4 v = {0u, 0u, 0u, 0u};
      int row = n0 + r;
      if (row < n) v = *(const u32x4*)(A.xdst + (size_t)row * 128 + c);
      *(u32x4*)(dstl + r * 136 + c) = v;
    }
  }

  // ---- preload this wave's 16 B fragments (2 h x 2 jt x 4 ks); latency hides under barrier ----
  const unsigned short* Wg[2] = { A.Wl, A.Wr };
  bf16x8 breg[2][2][4];
  #pragma unroll
  for (int h = 0; h < 2; ++h) {
    const unsigned short* wb = Wg[h] + (size_t)(wave * 32 + lr) * 128 + kb;
    #pragma unroll
    for (int jt = 0; jt < 2; ++jt)
      #pragma unroll
      for (int ks = 0; ks < 4; ++ks)
        breg[h][jt][ks] = *(const bf16x8*)(wb + jt * 16 * 128 + ks * 32);
  }
  __syncthreads();

  // ---- pure LDS + register MFMA loop: 32 ds_read_b128, 64 MFMA ----
  f32x4 acc[4][2] = {};           // [row tile][col tile], statically indexed
  #pragma unroll
  for (int h = 0; h < 2; ++h) {
    const unsigned short* Abase = lds + h * 64 * 136 + lr * 136 + kb;
    #pragma unroll
    for (int rt = 0; rt < 4; ++rt) {
      #pragma unroll
      for (int ks = 0; ks < 4; ++ks) {
        bf16x8 a = *(const bf16x8*)(Abase + rt * 16 * 136 + ks * 32);
        acc[rt][0] = __builtin_amdgcn_mfma_f32_16x16x32_bf16(a, breg[h][0][ks], acc[rt][0], 0, 0, 0);
        acc[rt][1] = __builtin_amdgcn_mfma_f32_16x16x32_bf16(a, breg[h][1][ks], acc[rt][1], 0, 0, 0);
      }
    }
  }

  // C/D layout: col = lane&15, row = (lane>>4)*4 + reg  [verified m89/m91]
  #pragma unroll
  for (int jt = 0; jt < 2; ++jt) {
    int col = wave * 32 + jt * 16 + lr;
    float bv = A.bias[col];
    #pragma unroll
    for (int rt = 0; rt < 4; ++rt) {
      int rbase = n0 + rt * 16 + (lane >> 4) * 4;
      #pragma unroll
      for (int i = 0; i < 4; ++i) {
        int row = rbase + i;
        if (row < n) {
          float v = acc[rt][jt][i] + bv;
          if (RELU_BF16) {
            v = v > 0.f ? v : 0.f;
            ((unsigned short*)A.out)[(size_t)row * 128 + col] = f2bf(v);
          } else {
            ((float*)A.out)[(size_t)row * 128 + col] = v;
          }
        }
      }
    }
  }
}

extern "C" void kernel_launch(void* const* d_in, const int* in_sizes, int n_in,
                              void* d_out, int out_size, void* d_ws, size_t ws_size,
                              hipStream_t stream) {
  const float* xp = (const float*)d_in[0];
  const float* xt = (const float*)d_in[1];
  const int* ei_pt = (const int*)d_in[2];
  const int* ei_tp = (const int*)d_in[3];
  WPtrs wp;
  for (int i = 0; i < 8; ++i) wp.p[i] = (const float*)d_in[4 + i];
  const float* bl0_pt = (const float*)d_in[12];
  const float* bl0_tp = (const float*)d_in[13];
  const float* bl1_pt = (const float*)d_in[14];
  const float* bl1_tp = (const float*)d_in[15];
  float* out = (float*)d_out;     // [o_player (N*128) | o_team (N*128)]

  const int N = in_sizes[0] / 128;
  const int E = in_sizes[2] / 2;
  const size_t NB = (size_t)N * 128 * 2;    // bf16 feature matrix bytes

  char* ws = (char*)d_ws;
  size_t off = 0;
  auto alloc = [&](size_t bytes) -> void* {
    off = (off + 255) & ~(size_t)255;
    void* p = ws + off; off += bytes; return p;
  };
  unsigned short* xp_bf  = (unsigned short*)alloc(NB);
  unsigned short* xt_bf  = (unsigned short*)alloc(NB);
  unsigned short* hp_bf  = (unsigned short*)alloc(NB);
  unsigned short* ht_bf  = (unsigned short*)alloc(NB);
  unsigned short* wbf    = (unsigned short*)alloc(8 * 16384 * 2);
  int* cnt    = (int*)alloc((size_t)2 * N * 4);
  int* rowptr = (int*)alloc((size_t)2 * N * 4);
  int* cursor = (int*)alloc((size_t)2 * N * 4);
  int* incl   = (int*)alloc((size_t)2 * N * 4);
  int* ssrc   = (int*)alloc((size_t)2 * E * 4);
  int* bsum   = (int*)alloc(2 * 128 * 4);

  const int nx = N * 128;
  // fp32 -> bf16 conversions
  cvt_x<<<dim3((nx / 8 + 255) / 256, 2), 256, 0, stream>>>(xp, xt, xp_bf, xt_bf, nx);
  cvt_w<<<dim3(8, 8), 256, 0, stream>>>(wp, wbf);

  // CSR build, both relations per launch (reused by both layers)
  const int SCB = (N + 1023) / 1024;
  hipMemsetAsync(cnt, 0, (size_t)2 * N * 4, stream);
  hist2_k<<<dim3((E + 255) / 256, 2), 256, 0, stream>>>(ei_pt, ei_tp, cnt, E, N);
  scan_a2<<<dim3(SCB, 2), 1024, 0, stream>>>(cnt, incl, bsum, N);
  scan_b2<<<dim3(1, 2), 128, 0, stream>>>(bsum, SCB);
  scan_c2<<<dim3((N + 255) / 256, 2), 256, 0, stream>>>(cnt, incl, bsum, rowptr, cursor, N);
  reorder2_k<<<dim3((E + 255) / 256, 2), 256, 0, stream>>>(ei_pt, ei_tp, cursor, ssrc, E, N);

  const int LNB = (N + 63) / 64;
  // relation 0 = pt (dst type team), relation 1 = tp (dst type player)
  // ---- layer 0 (relu, bf16 out) ----
  FusedArgs l0a = { xp_bf, xt_bf, rowptr,     cnt,     ssrc,     wbf + 0*16384, wbf + 1*16384, bl0_pt, ht_bf };
  FusedArgs l0b = { xt_bf, xp_bf, rowptr + N, cnt + N, ssrc + E, wbf + 2*16384, wbf + 3*16384, bl0_tp, hp_bf };
  fused_k<1><<<dim3(LNB, 2), 256, 0, stream>>>(l0a, l0b, N);
  // ---- layer 1 (f32 out) ----
  FusedArgs l1a = { hp_bf, ht_bf, rowptr,     cnt,     ssrc,     wbf + 4*16384, wbf + 5*16384, bl1_pt, out + (size_t)N * 128 };
  FusedArgs l1b = { ht_bf, hp_bf, rowptr + N, cnt + N, ssrc + E, wbf + 6*16384, wbf + 7*16384, bl1_tp, out };
  fused_k<0><<<dim3(LNB, 2), 256, 0, stream>>>(l1a, l1b, N);
}

// Round 5
// 503.944 us; speedup vs baseline: 1.4704x; 1.1185x over previous
//
#include <hip/hip_runtime.h>
#include <hip/hip_bf16.h>
#include <stdint.h>

typedef __attribute__((ext_vector_type(8))) short bf16x8;
typedef __attribute__((ext_vector_type(4))) float f32x4;
typedef __attribute__((ext_vector_type(4))) unsigned int u32x4;

__device__ __forceinline__ unsigned short f2bf(float f) {
  union { float f; unsigned int u; } c; c.f = f;
  unsigned int u = c.u;
  u += 0x7FFFu + ((u >> 16) & 1u);   // round-to-nearest-even
  return (unsigned short)(u >> 16);
}
__device__ __forceinline__ float bf2f(unsigned short b) {
  union { unsigned int u; float f; } c; c.u = ((unsigned int)b) << 16;
  return c.f;
}
__device__ __forceinline__ void acc8(const u32x4& v, float* a) {
  a[0] += bf2f((unsigned short)(v[0] & 0xFFFF)); a[1] += bf2f((unsigned short)(v[0] >> 16));
  a[2] += bf2f((unsigned short)(v[1] & 0xFFFF)); a[3] += bf2f((unsigned short)(v[1] >> 16));
  a[4] += bf2f((unsigned short)(v[2] & 0xFFFF)); a[5] += bf2f((unsigned short)(v[2] >> 16));
  a[6] += bf2f((unsigned short)(v[3] & 0xFFFF)); a[7] += bf2f((unsigned short)(v[3] >> 16));
}

// ---- convert two fp32 arrays to bf16 (blockIdx.y selects which) ----
__global__ void cvt_x(const float* __restrict__ a, const float* __restrict__ b,
                      unsigned short* __restrict__ oa, unsigned short* __restrict__ ob, int n) {
  const float* src = blockIdx.y ? b : a;
  unsigned short* dst = blockIdx.y ? ob : oa;
  int i = (blockIdx.x * 256 + threadIdx.x) * 8;
  if (i >= n) return;
  float4 v0 = *(const float4*)(src + i);
  float4 v1 = *(const float4*)(src + i + 4);
  u32x4 o;
  o[0] = (unsigned int)f2bf(v0.x) | ((unsigned int)f2bf(v0.y) << 16);
  o[1] = (unsigned int)f2bf(v0.z) | ((unsigned int)f2bf(v0.w) << 16);
  o[2] = (unsigned int)f2bf(v1.x) | ((unsigned int)f2bf(v1.y) << 16);
  o[3] = (unsigned int)f2bf(v1.z) | ((unsigned int)f2bf(v1.w) << 16);
  *(u32x4*)(dst + i) = o;
}

struct WPtrs { const float* p[8]; };

// ---- convert the 8 [128x128] weight matrices to bf16 ----
__global__ void cvt_w(WPtrs w, unsigned short* __restrict__ out) {
  int wi = blockIdx.y;
  int i = (blockIdx.x * 256 + threadIdx.x) * 8;   // 16384 elems -> 8 blocks in x
  const float* src = w.p[wi];
  float4 v0 = *(const float4*)(src + i);
  float4 v1 = *(const float4*)(src + i + 4);
  u32x4 o;
  o[0] = (unsigned int)f2bf(v0.x) | ((unsigned int)f2bf(v0.y) << 16);
  o[1] = (unsigned int)f2bf(v0.z) | ((unsigned int)f2bf(v0.w) << 16);
  o[2] = (unsigned int)f2bf(v1.x) | ((unsigned int)f2bf(v1.y) << 16);
  o[3] = (unsigned int)f2bf(v1.z) | ((unsigned int)f2bf(v1.w) << 16);
  *(u32x4*)(out + wi * 16384 + i) = o;
}

// ---- counting-sort pipeline, both relations per launch (blockIdx.y) ----
__global__ void hist2_k(const int* __restrict__ ei0, const int* __restrict__ ei1,
                        int* __restrict__ cnt, int E, int N) {
  const int* ei = blockIdx.y ? ei1 : ei0;
  int* c = cnt + blockIdx.y * N;
  int e = blockIdx.x * 256 + threadIdx.x;
  if (e < E) atomicAdd(&c[ei[E + e]], 1);     // ei row 1 = dst
}

__global__ void scan_a2(const int* __restrict__ cnt, int* __restrict__ incl,
                        int* __restrict__ bsum, int n) {
  const int* in = cnt + blockIdx.y * n;
  int* out = incl + blockIdx.y * n;
  int* bs = bsum + blockIdx.y * 128;
  __shared__ int sm[1024];
  int i = blockIdx.x * 1024 + threadIdx.x;
  int v = (i < n) ? in[i] : 0;
  sm[threadIdx.x] = v;
  __syncthreads();
  for (int off = 1; off < 1024; off <<= 1) {
    int t = (threadIdx.x >= off) ? sm[threadIdx.x - off] : 0;
    __syncthreads();
    sm[threadIdx.x] += t;
    __syncthreads();
  }
  if (i < n) out[i] = sm[threadIdx.x];
  if (threadIdx.x == 1023) bs[blockIdx.x] = sm[1023];
}

__global__ void scan_b2(int* __restrict__ bsum, int nb) {
  int* bs = bsum + blockIdx.y * 128;
  __shared__ int sm[128];
  int t = threadIdx.x;
  int v = (t < nb) ? bs[t] : 0;
  sm[t] = v;
  __syncthreads();
  for (int off = 1; off < 128; off <<= 1) {
    int u = (t >= off) ? sm[t - off] : 0;
    __syncthreads();
    sm[t] += u;
    __syncthreads();
  }
  if (t < nb) bs[t] = sm[t] - v;   // exclusive block offsets
}

__global__ void scan_c2(const int* __restrict__ cnt, const int* __restrict__ incl,
                        const int* __restrict__ bsum, int* __restrict__ rowptr,
                        int* __restrict__ cursor, int n) {
  int y = blockIdx.y;
  int i = blockIdx.x * 256 + threadIdx.x;
  if (i >= n) return;
  int e = incl[y * n + i] - cnt[y * n + i] + bsum[y * 128 + (i >> 10)];
  rowptr[y * n + i] = e;
  cursor[y * n + i] = e;
}

__global__ void reorder2_k(const int* __restrict__ ei0, const int* __restrict__ ei1,
                           int* __restrict__ cursor, int* __restrict__ ssrc, int E, int N) {
  const int* ei = blockIdx.y ? ei1 : ei0;
  int* cur = cursor + blockIdx.y * N;
  int* ss = ssrc + blockIdx.y * E;
  int e = blockIdx.x * 256 + threadIdx.x;
  if (e >= E) return;
  int s = ei[e];          // src
  int d = ei[E + e];      // dst
  int pos = atomicAdd(&cur[d], 1);
  ss[pos] = s;
}

// ---- fused gather-mean + dual matmul ----
// out = mean_csr(xsrc) @ Wl^T + xdst @ Wr^T + bias (+relu->bf16 | ->f32)
// block = 256 threads (4 waves), tile = 64 rows x 128 cols; grid.y picks relation.
// Gather: batches of 8 clamped independent loads (mean deg = 6 -> usually ONE
// 2-latency-hop batch per node, vs the serial chain of round 4).
// Epilogue: acc -> LDS -> coalesced full-row stores (kills write-allocate RMW).
struct FusedArgs {
  const unsigned short* xsrc; const unsigned short* xdst;
  const int* rowptr; const int* cnt; const int* ssrc;
  const unsigned short* Wl; const unsigned short* Wr;
  const float* bias; void* out;
};

template<int RELU_BF16>
__global__ __launch_bounds__(256, 4) void fused_k(FusedArgs f0, FusedArgs f1, int n) {
  FusedArgs A = blockIdx.y ? f1 : f0;
  __shared__ __align__(16) unsigned short lds[2 * 64 * 136];   // 34816 B
  int n0 = blockIdx.x * 64;
  int tid = threadIdx.x;
  int wave = tid >> 6, lane = tid & 63;
  int lr = lane & 15;             // A row-in-16 / B col-in-16
  int kb = (lane >> 4) * 8;       // k sub-offset within the 32-wide K step

  // ---- phase 1: gather-mean into lds[0] ----
  {
    int g = tid >> 4;             // 16-lane group id = node-in-sweep
    int q = (tid & 15) * 8;       // bf16 column offset
    // prefetch node descriptors for all 4 sweeps (8 independent loads)
    int begs[4], degs[4];
    #pragma unroll
    for (int s = 0; s < 4; ++s) {
      int nd = n0 + s * 16 + g;
      bool ok = nd < n;
      begs[s] = ok ? A.rowptr[nd] : 0;
      degs[s] = ok ? A.cnt[nd] : 0;
    }
    #pragma unroll
    for (int s = 0; s < 4; ++s) {
      int beg = begs[s], deg = degs[s];
      float a[8] = {0.f,0.f,0.f,0.f,0.f,0.f,0.f,0.f};
      if (deg > 0) {
        int elast = beg + deg - 1;
        int t = 0;
        do {
          // 8 independent clamped index loads
          int i0 = A.ssrc[min(beg + t + 0, elast)];
          int i1 = A.ssrc[min(beg + t + 1, elast)];
          int i2 = A.ssrc[min(beg + t + 2, elast)];
          int i3 = A.ssrc[min(beg + t + 3, elast)];
          int i4 = A.ssrc[min(beg + t + 4, elast)];
          int i5 = A.ssrc[min(beg + t + 5, elast)];
          int i6 = A.ssrc[min(beg + t + 6, elast)];
          int i7 = A.ssrc[min(beg + t + 7, elast)];
          // 8 independent row loads
          u32x4 v0 = *(const u32x4*)(A.xsrc + (size_t)i0 * 128 + q);
          u32x4 v1 = *(const u32x4*)(A.xsrc + (size_t)i1 * 128 + q);
          u32x4 v2 = *(const u32x4*)(A.xsrc + (size_t)i2 * 128 + q);
          u32x4 v3 = *(const u32x4*)(A.xsrc + (size_t)i3 * 128 + q);
          u32x4 v4 = *(const u32x4*)(A.xsrc + (size_t)i4 * 128 + q);
          u32x4 v5 = *(const u32x4*)(A.xsrc + (size_t)i5 * 128 + q);
          u32x4 v6 = *(const u32x4*)(A.xsrc + (size_t)i6 * 128 + q);
          u32x4 v7 = *(const u32x4*)(A.xsrc + (size_t)i7 * 128 + q);
          int rem = deg - t;      // group-uniform predication
          if (rem > 0) acc8(v0, a);
          if (rem > 1) acc8(v1, a);
          if (rem > 2) acc8(v2, a);
          if (rem > 3) acc8(v3, a);
          if (rem > 4) acc8(v4, a);
          if (rem > 5) acc8(v5, a);
          if (rem > 6) acc8(v6, a);
          if (rem > 7) acc8(v7, a);
          t += 8;
        } while (t < deg);
      }
      float inv = deg > 0 ? 1.0f / (float)deg : 0.0f;
      u32x4 o;
      o[0] = (unsigned int)f2bf(a[0]*inv) | ((unsigned int)f2bf(a[1]*inv) << 16);
      o[1] = (unsigned int)f2bf(a[2]*inv) | ((unsigned int)f2bf(a[3]*inv) << 16);
      o[2] = (unsigned int)f2bf(a[4]*inv) | ((unsigned int)f2bf(a[5]*inv) << 16);
      o[3] = (unsigned int)f2bf(a[6]*inv) | ((unsigned int)f2bf(a[7]*inv) << 16);
      *(u32x4*)(lds + (s * 16 + g) * 136 + q) = o;
    }
  }

  // ---- phase 1b: copy xdst tile into lds[1] ----
  {
    unsigned short* dstl = lds + 64 * 136;
    #pragma unroll
    for (int it = 0; it < 4; ++it) {
      int li = (it * 256 + tid) * 8;
      int r = li >> 7, c = li & 127;
      u32x4 v = {0u, 0u, 0u, 0u};
      int row = n0 + r;
      if (row < n) v = *(const u32x4*)(A.xdst + (size_t)row * 128 + c);
      *(u32x4*)(dstl + r * 136 + c) = v;
    }
  }

  // ---- preload this wave's 16 B fragments (2 h x 2 jt x 4 ks) ----
  const unsigned short* Wg[2] = { A.Wl, A.Wr };
  bf16x8 breg[2][2][4];
  #pragma unroll
  for (int h = 0; h < 2; ++h) {
    const unsigned short* wb = Wg[h] + (size_t)(wave * 32 + lr) * 128 + kb;
    #pragma unroll
    for (int jt = 0; jt < 2; ++jt)
      #pragma unroll
      for (int ks = 0; ks < 4; ++ks)
        breg[h][jt][ks] = *(const bf16x8*)(wb + jt * 16 * 128 + ks * 32);
  }
  __syncthreads();

  // ---- pure LDS + register MFMA loop: 32 ds_read_b128, 64 MFMA ----
  f32x4 acc[4][2] = {};           // [row tile][col tile], statically indexed
  #pragma unroll
  for (int h = 0; h < 2; ++h) {
    const unsigned short* Abase = lds + h * 64 * 136 + lr * 136 + kb;
    #pragma unroll
    for (int rt = 0; rt < 4; ++rt) {
      #pragma unroll
      for (int ks = 0; ks < 4; ++ks) {
        bf16x8 a = *(const bf16x8*)(Abase + rt * 16 * 136 + ks * 32);
        acc[rt][0] = __builtin_amdgcn_mfma_f32_16x16x32_bf16(a, breg[h][0][ks], acc[rt][0], 0, 0, 0);
        acc[rt][1] = __builtin_amdgcn_mfma_f32_16x16x32_bf16(a, breg[h][1][ks], acc[rt][1], 0, 0, 0);
      }
    }
  }

  // ---- epilogue: acc -> LDS (overlay) -> coalesced full-row global stores ----
  // C/D layout: col = lane&15, row = (lane>>4)*4 + reg  [verified m89/m91]
  __syncthreads();                // all A-tile reads done; safe to overlay lds
  if (RELU_BF16) {
    unsigned short* st = (unsigned short*)lds;   // 64 x 128, stride 136
    #pragma unroll
    for (int jt = 0; jt < 2; ++jt) {
      int col = wave * 32 + jt * 16 + lr;
      float bv = A.bias[col];
      #pragma unroll
      for (int rt = 0; rt < 4; ++rt) {
        int rloc = rt * 16 + (lane >> 4) * 4;
        #pragma unroll
        for (int i = 0; i < 4; ++i) {
          float v = acc[rt][jt][i] + bv;
          v = v > 0.f ? v : 0.f;
          st[(rloc + i) * 136 + col] = f2bf(v);
        }
      }
    }
    __syncthreads();
    #pragma unroll
    for (int it = 0; it < 4; ++it) {
      int flat = (it * 256 + tid) * 8;           // 8192 bf16
      int r = flat >> 7, c = flat & 127;
      if (n0 + r < n) {
        u32x4 v = *(const u32x4*)(st + r * 136 + c);
        *(u32x4*)((unsigned short*)A.out + (size_t)(n0 + r) * 128 + c) = v;
      }
    }
  } else {
    float* st = (float*)lds;                     // 64 x 128, stride 132 (33024 B)
    #pragma unroll
    for (int jt = 0; jt < 2; ++jt) {
      int col = wave * 32 + jt * 16 + lr;
      float bv = A.bias[col];
      #pragma unroll
      for (int rt = 0; rt < 4; ++rt) {
        int rloc = rt * 16 + (lane >> 4) * 4;
        #pragma unroll
        for (int i = 0; i < 4; ++i)
          st[(rloc + i) * 132 + col] = acc[rt][jt][i] + bv;
      }
    }
    __syncthreads();
    #pragma unroll
    for (int it = 0; it < 8; ++it) {
      int flat = (it * 256 + tid) * 4;           // 8192 f32
      int r = flat >> 7, c = flat & 127;
      if (n0 + r < n) {
        u32x4 v = *(const u32x4*)(st + r * 132 + c);
        *(u32x4*)((float*)A.out + (size_t)(n0 + r) * 128 + c) = v;
      }
    }
  }
}

extern "C" void kernel_launch(void* const* d_in, const int* in_sizes, int n_in,
                              void* d_out, int out_size, void* d_ws, size_t ws_size,
                              hipStream_t stream) {
  const float* xp = (const float*)d_in[0];
  const float* xt = (const float*)d_in[1];
  const int* ei_pt = (const int*)d_in[2];
  const int* ei_tp = (const int*)d_in[3];
  WPtrs wp;
  for (int i = 0; i < 8; ++i) wp.p[i] = (const float*)d_in[4 + i];
  const float* bl0_pt = (const float*)d_in[12];
  const float* bl0_tp = (const float*)d_in[13];
  const float* bl1_pt = (const float*)d_in[14];
  const float* bl1_tp = (const float*)d_in[15];
  float* out = (float*)d_out;     // [o_player (N*128) | o_team (N*128)]

  const int N = in_sizes[0] / 128;
  const int E = in_sizes[2] / 2;
  const size_t NB = (size_t)N * 128 * 2;    // bf16 feature matrix bytes

  char* ws = (char*)d_ws;
  size_t off = 0;
  auto alloc = [&](size_t bytes) -> void* {
    off = (off + 255) & ~(size_t)255;
    void* p = ws + off; off += bytes; return p;
  };
  unsigned short* xp_bf  = (unsigned short*)alloc(NB);
  unsigned short* xt_bf  = (unsigned short*)alloc(NB);
  unsigned short* hp_bf  = (unsigned short*)alloc(NB);
  unsigned short* ht_bf  = (unsigned short*)alloc(NB);
  unsigned short* wbf    = (unsigned short*)alloc(8 * 16384 * 2);
  int* cnt    = (int*)alloc((size_t)2 * N * 4);
  int* rowptr = (int*)alloc((size_t)2 * N * 4);
  int* cursor = (int*)alloc((size_t)2 * N * 4);
  int* incl   = (int*)alloc((size_t)2 * N * 4);
  int* ssrc   = (int*)alloc((size_t)2 * E * 4);
  int* bsum   = (int*)alloc(2 * 128 * 4);

  const int nx = N * 128;
  // fp32 -> bf16 conversions
  cvt_x<<<dim3((nx / 8 + 255) / 256, 2), 256, 0, stream>>>(xp, xt, xp_bf, xt_bf, nx);
  cvt_w<<<dim3(8, 8), 256, 0, stream>>>(wp, wbf);

  // CSR build, both relations per launch (reused by both layers)
  const int SCB = (N + 1023) / 1024;
  hipMemsetAsync(cnt, 0, (size_t)2 * N * 4, stream);
  hist2_k<<<dim3((E + 255) / 256, 2), 256, 0, stream>>>(ei_pt, ei_tp, cnt, E, N);
  scan_a2<<<dim3(SCB, 2), 1024, 0, stream>>>(cnt, incl, bsum, N);
  scan_b2<<<dim3(1, 2), 128, 0, stream>>>(bsum, SCB);
  scan_c2<<<dim3((N + 255) / 256, 2), 256, 0, stream>>>(cnt, incl, bsum, rowptr, cursor, N);
  reorder2_k<<<dim3((E + 255) / 256, 2), 256, 0, stream>>>(ei_pt, ei_tp, cursor, ssrc, E, N);

  const int LNB = (N + 63) / 64;
  // relation 0 = pt (dst type team), relation 1 = tp (dst type player)
  // ---- layer 0 (relu, bf16 out) ----
  FusedArgs l0a = { xp_bf, xt_bf, rowptr,     cnt,     ssrc,     wbf + 0*16384, wbf + 1*16384, bl0_pt, ht_bf };
  FusedArgs l0b = { xt_bf, xp_bf, rowptr + N, cnt + N, ssrc + E, wbf + 2*16384, wbf + 3*16384, bl0_tp, hp_bf };
  fused_k<1><<<dim3(LNB, 2), 256, 0, stream>>>(l0a, l0b, N);
  // ---- layer 1 (f32 out) ----
  FusedArgs l1a = { hp_bf, ht_bf, rowptr,     cnt,     ssrc,     wbf + 4*16384, wbf + 5*16384, bl1_pt, out + (size_t)N * 128 };
  FusedArgs l1b = { ht_bf, hp_bf, rowptr + N, cnt + N, ssrc + E, wbf + 6*16384, wbf + 7*16384, bl1_tp, out };
  fused_k<0><<<dim3(LNB, 2), 256, 0, stream>>>(l1a, l1b, N);
}